// Round 5
// baseline (285.911 us; speedup 1.0000x reference)
//
#include <hip/hip_runtime.h>
#include <math.h>

typedef __attribute__((ext_vector_type(8))) short short8;
typedef __attribute__((ext_vector_type(4))) float f32x4;
typedef __attribute__((ext_vector_type(4))) int i32x4;

#define NN 2048
#define LL 64
#define DD 128
#define BBATCH 8
#define LOCB 8

// packed-weight offsets (bf16 element units)
#define PK_Q    0
#define PK_V    16384
#define PK_OUT  32768
#define PK_POI  49152
#define PK_SAT  57344
#define PK_LOC  73728
#define PK_XL   77824
#define PK_IMP  94208
#define PK_UNC  225280
#define PK_TOTAL 290816
#define KW_BLOCKS 1136   // PK_TOTAL / 256 exactly

__device__ __forceinline__ unsigned short f2bf(float f) {
  unsigned u = __float_as_uint(f);
  u += 0x7fffu + ((u >> 16) & 1u);   // round-to-nearest-even
  return (unsigned short)(u >> 16);
}
__device__ __forceinline__ float sigm(float x) { return 1.0f / (1.0f + expf(-x)); }

// RNE-pack two f32 -> one u32 of 2x bf16, via schedulable builtins (no asm).
__device__ __forceinline__ unsigned bfpair(float lo, float hi) {
  unsigned a = __float_as_uint(lo);
  unsigned b = __float_as_uint(hi);
  a += 0x7fffu + ((a >> 16) & 1u);
  b += 0x7fffu + ((b >> 16) & 1u);
  return __builtin_amdgcn_perm(b, a, 0x07060302u);
}

struct Frag { short8 v[4]; };

// ---------------------------------------------------------------------------
// kWA: merged weight-pack (blocks 0..1135) + folded-C precompute (1136..1264).
// ---------------------------------------------------------------------------
__global__ __launch_bounds__(256) void kWA(
    const float* __restrict__ q_W, const float* __restrict__ v_W,
    const float* __restrict__ out_W, const float* __restrict__ poi_W,
    const float* __restrict__ sat_W, const float* __restrict__ loc_W,
    const float* __restrict__ xl_W, const float* __restrict__ imp_W,
    const float* __restrict__ unc_W1,
    const float* __restrict__ xl_b, const float* __restrict__ x_pe,
    const float* __restrict__ v_b,
    unsigned short* __restrict__ dst,
    unsigned short* __restrict__ ctswz, float* __restrict__ cb) {
  if (blockIdx.x < KW_BLOCKS) {
    int idx = blockIdx.x * 256 + threadIdx.x;
    const float* src;
    int K, local;
    if (idx < PK_V)        { src = q_W;   K = 128; local = idx - PK_Q; }
    else if (idx < PK_OUT) { src = v_W;   K = 128; local = idx - PK_V; }
    else if (idx < PK_POI) { src = out_W; K = 128; local = idx - PK_OUT; }
    else if (idx < PK_SAT) { src = poi_W; K = 64;  local = idx - PK_POI; }
    else if (idx < PK_LOC) { src = sat_W; K = 128; local = idx - PK_SAT; }
    else if (idx < PK_XL)  { src = loc_W; K = 32;  local = idx - PK_LOC; }
    else if (idx < PK_IMP) { src = xl_W;  K = 128; local = idx - PK_XL; }
    else if (idx < PK_UNC) { int l = idx - PK_IMP; int m = l >> 15; src = imp_W + m * 256 * 128; K = 256; local = l & 32767; }
    else                   { int l = idx - PK_UNC; int m = l >> 14; src = unc_W1 + m * 128 * 128; K = 128; local = l & 16383; }
    int e = local & 7, lane = (local >> 3) & 63, rest = local >> 9;
    int KT = K >> 5;
    int kt = rest % KT, j = rest / KT;
    int k = kt * 32 + (lane >> 4) * 8 + e;
    int col = j * 16 + (lane & 15);
    dst[idx] = f2bf(src[k * 128 + col]);
  } else {
    __shared__ float s1[128];
    __shared__ float s2[128];
    const int t = threadIdx.x;
    const int k = blockIdx.x - KW_BLOCKS;  // 0..128
    if (t < 128) s1[t] = (k < 128) ? xl_W[k * 128 + t] : (xl_b[t] + x_pe[t]);
    __syncthreads();
    if (t < 128) {
      float ac[4] = {0.f, 0.f, 0.f, 0.f};
      for (int j = 0; j < 128; j += 4) {
#pragma unroll
        for (int u = 0; u < 4; ++u) ac[u] += s1[j + u] * v_W[(j + u) * 128 + t];
      }
      float a1 = (ac[0] + ac[1]) + (ac[2] + ac[3]);
      if (k == 128) a1 += v_b[t];
      s2[t] = a1;
    }
    __syncthreads();
    if (t < 128) {
      float ac[4] = {0.f, 0.f, 0.f, 0.f};
      for (int j = 0; j < 128; j += 4) {
#pragma unroll
        for (int u = 0; u < 4; ++u) ac[u] += s2[j + u] * out_W[(j + u) * 128 + t];
      }
      float a2 = (ac[0] + ac[1]) + (ac[2] + ac[3]);
      if (k < 128) {
        int byte = (t * 256 + k * 2) ^ ((t & 7) << 4);
        ctswz[byte >> 1] = f2bf(a2);
      } else {
        cb[t] = a2;
      }
    }
  }
}

// ---------------------------------------------------------------------------
// kC: x_out = x @ C + cb, bf16 MFMA, transposed-D, depth-2 register prefetch,
// nontemporal streaming loads, occupancy forced to 4 blocks/CU (VGPR<=128).
// ---------------------------------------------------------------------------
__global__ __launch_bounds__(256, 4) void kC(const float* __restrict__ x,
                                             const unsigned short* __restrict__ ctswz,
                                             const float* __restrict__ cb,
                                             float* __restrict__ out) {
  __shared__ __align__(16) unsigned short lds[128 * 128];
  __shared__ float cbl[128];
  const int t = threadIdx.x;
  for (int i = t; i < 2048; i += 256)
    ((f32x4*)lds)[i] = ((const f32x4*)ctswz)[i];
  if (t < 128) cbl[t] = cb[t];
  __syncthreads();

  const int lane = t & 63;
  const int r16 = lane & 15;
  const int g4 = lane >> 4;

  int kofs[4];
#pragma unroll
  for (int kt = 0; kt < 4; ++kt)
    kofs[kt] = (kt * 64 + g4 * 16) ^ ((r16 & 7) << 4);

  const char* ldsb = (const char*)lds;
  const int gw = blockIdx.x * 4 + (t >> 6);

  const float* xw = x + ((size_t)gw * 16 + r16) * 128 + g4 * 8;
  const size_t TS = (size_t)8192 * 16 * 128;  // elements per tile step

  auto loadx = [&](f32x4* r0, f32x4* r1, const float* p) {
#pragma unroll
    for (int kt = 0; kt < 4; ++kt) {
      r0[kt] = __builtin_nontemporal_load((const f32x4*)(p + kt * 32));
      r1[kt] = __builtin_nontemporal_load((const f32x4*)(p + kt * 32 + 4));
    }
  };

  auto pack = [&](const f32x4* r0, const f32x4* r1) -> Frag {
    Frag f;
#pragma unroll
    for (int kt = 0; kt < 4; ++kt) {
      i32x4 p;
      p[0] = (int)bfpair(r0[kt][0], r0[kt][1]);
      p[1] = (int)bfpair(r0[kt][2], r0[kt][3]);
      p[2] = (int)bfpair(r1[kt][0], r1[kt][1]);
      p[3] = (int)bfpair(r1[kt][2], r1[kt][3]);
      f.v[kt] = __builtin_bit_cast(short8, p);
    }
    return f;
  };

  auto jloop = [&](const Frag& f, int it) {
    float* orow = out + (((size_t)gw + (size_t)it * 8192) * 16 + r16) * 128 + g4 * 4;
#pragma unroll
    for (int j = 0; j < 8; ++j) {
      f32x4 acc = {0.f, 0.f, 0.f, 0.f};
      const int cbyte = (j * 16 + r16) << 8;
#pragma unroll
      for (int kt = 0; kt < 4; ++kt) {
        short8 a = *(const short8*)(ldsb + cbyte + kofs[kt]);
        acc = __builtin_amdgcn_mfma_f32_16x16x32_bf16(a, f.v[kt], acc, 0, 0, 0);
      }
      f32x4 cbj = *(const f32x4*)(cbl + j * 16 + g4 * 4);
      acc += cbj;
      *(f32x4*)(orow + j * 16) = acc;
    }
  };

  f32x4 rA0[4], rA1[4], rB0[4], rB1[4];
  loadx(rA0, rA1, xw);
  loadx(rB0, rB1, xw + TS);

#pragma unroll
  for (int it = 0; it < 8; it += 2) {
    Frag fA = pack(rA0, rA1);
    if (it + 2 < 8) loadx(rA0, rA1, xw + (size_t)(it + 2) * TS);
    jloop(fA, it);
    Frag fB = pack(rB0, rB1);
    if (it + 3 < 8) loadx(rB0, rB1, xw + (size_t)(it + 3) * TS);
    jloop(fB, it + 1);
  }
}

// ---------------------------------------------------------------------------
// kB: MFMA selector. 256 blocks x 256 threads; block = 8 locations; wave = m.
// ---------------------------------------------------------------------------
__device__ __forceinline__ short8 ldb(const unsigned short* pkW, int j, int kt, int KT) {
  return *(const short8*)(pkW + (size_t)(((j * KT + kt) * 64) + (threadIdx.x & 63)) * 8);
}

__global__ __launch_bounds__(256) void kB(
    const float* __restrict__ x, const float* __restrict__ poi,
    const float* __restrict__ sat, const float* __restrict__ loc,
    const float* __restrict__ state,
    const float* __restrict__ poi_b, const float* __restrict__ poi_pe,
    const float* __restrict__ sat_b, const float* __restrict__ sat_pe,
    const float* __restrict__ loc_b, const float* __restrict__ loc_pe,
    const float* __restrict__ xl_b, const float* __restrict__ x_pe,
    const float* __restrict__ q_b, const float* __restrict__ v_b,
    const float* __restrict__ imp_b, const float* __restrict__ unc_b1,
    const float* __restrict__ unc_W2, const float* __restrict__ unc_b2,
    const unsigned short* __restrict__ pk,
    float* __restrict__ emb1, float* __restrict__ bm) {
  // sA: [0..3]=q tiles, [4..7]=qu tiles, [8..11]=va tiles, [12]=xb tile
  __shared__ __align__(16) unsigned short sA[13 * 2048];
  __shared__ float s_full[LOCB][4];

  const int t = threadIdx.x;
  const int m = t >> 6;
  const int lane = t & 63;
  const int r16 = lane & 15, g4 = lane >> 4;
  const int n0 = blockIdx.x * LOCB;

  for (int i = t; i < 13 * 1024; i += 256) ((unsigned*)sA)[i] = 0u;
  __syncthreads();

  // P0: xb = mean_b x[b, n0+l, 0, :]
  for (int s = t; s < LOCB * 128; s += 256) {
    int l = s >> 7, d = s & 127;
    const float* xp = x + ((size_t)(n0 + l) * LL) * DD + d;
    float acc = 0.f;
#pragma unroll
    for (int b = 0; b < BBATCH; ++b) acc += xp[(size_t)b * NN * LL * DD];
    sA[12 * 2048 + ((l * 128 + d) ^ ((l & 7) << 3))] = f2bf(acc * 0.125f);
  }
  __syncthreads();

  // ---- P1: q[m] = input_m @ W_m + b_m + pe_m
  {
    const int KTm = (m == 0) ? 2 : ((m == 2) ? 1 : 4);
    const unsigned short* pkW =
        pk + (m == 0 ? PK_POI : m == 1 ? PK_SAT : m == 2 ? PK_LOC : PK_XL);
    const float* bb = (m == 0) ? poi_b : (m == 1) ? sat_b : (m == 2) ? loc_b : xl_b;
    const float* pe = (m == 0) ? poi_pe : (m == 1) ? sat_pe : (m == 2) ? loc_pe : x_pe;

    short8 af[4];
#pragma unroll
    for (int kt = 0; kt < 4; ++kt) af[kt] = (short8)0;
    if (m < 3) {
      const float* src = (m == 0) ? poi : (m == 1) ? sat : loc;
      const int KD = (m == 0) ? 64 : (m == 1) ? 128 : 32;
      const int locA = (r16 < LOCB) ? r16 : (LOCB - 1);
      const float* ar = src + (size_t)(n0 + locA) * KD + g4 * 8;
#pragma unroll
      for (int kt = 0; kt < 4; ++kt) {
        if (kt < KTm) {
          f32x4 v0 = *(const f32x4*)(ar + kt * 32);
          f32x4 v1 = *(const f32x4*)(ar + kt * 32 + 4);
          short8 a;
          a[0] = (short)f2bf(v0[0]); a[1] = (short)f2bf(v0[1]);
          a[2] = (short)f2bf(v0[2]); a[3] = (short)f2bf(v0[3]);
          a[4] = (short)f2bf(v1[0]); a[5] = (short)f2bf(v1[1]);
          a[6] = (short)f2bf(v1[2]); a[7] = (short)f2bf(v1[3]);
          af[kt] = a;
        }
      }
    } else {
      const unsigned short* tile = sA + 12 * 2048;
#pragma unroll
      for (int kt = 0; kt < 4; ++kt)
        af[kt] = *(const short8*)(tile + ((r16 * 128 + kt * 32 + g4 * 8) ^ ((r16 & 7) << 3)));
    }

    unsigned short* tq = sA + m * 2048;
#pragma unroll
    for (int j = 0; j < 8; ++j) {
      f32x4 acc = {0.f, 0.f, 0.f, 0.f};
#pragma unroll
      for (int kt = 0; kt < 4; ++kt)
        if (kt < KTm) acc = __builtin_amdgcn_mfma_f32_16x16x32_bf16(af[kt], ldb(pkW, j, kt, KTm), acc, 0, 0, 0);
      const int bcol = j * 16 + r16;
      const float badd = bb[bcol] + pe[bcol];
      if (g4 < 2) {
#pragma unroll
        for (int r = 0; r < 4; ++r) {
          int row = g4 * 4 + r;
          tq[(row * 128 + bcol) ^ ((row & 7) << 3)] = f2bf(acc[r] + badd);
        }
      }
    }
  }

  // ---- P2: qu = q@q_W + q_b ; va = q@v_W + v_b
  {
    const unsigned short* tile = sA + m * 2048;
    short8 aq[4];
#pragma unroll
    for (int kt = 0; kt < 4; ++kt)
      aq[kt] = *(const short8*)(tile + ((r16 * 128 + kt * 32 + g4 * 8) ^ ((r16 & 7) << 3)));
    unsigned short* tu = sA + (4 + m) * 2048;
    unsigned short* tv = sA + (8 + m) * 2048;
#pragma unroll
    for (int j = 0; j < 8; ++j) {
      f32x4 aQ = {0.f, 0.f, 0.f, 0.f}, aV = {0.f, 0.f, 0.f, 0.f};
#pragma unroll
      for (int kt = 0; kt < 4; ++kt) {
        aQ = __builtin_amdgcn_mfma_f32_16x16x32_bf16(aq[kt], ldb(pk + PK_Q, j, kt, 4), aQ, 0, 0, 0);
        aV = __builtin_amdgcn_mfma_f32_16x16x32_bf16(aq[kt], ldb(pk + PK_V, j, kt, 4), aV, 0, 0, 0);
      }
      const int bcol = j * 16 + r16;
      const float bq = q_b[bcol], bv = v_b[bcol];
      if (g4 < 2) {
#pragma unroll
        for (int r = 0; r < 4; ++r) {
          int row = g4 * 4 + r;
          tu[(row * 128 + bcol) ^ ((row & 7) << 3)] = f2bf(aQ[r] + bq);
          tv[(row * 128 + bcol) ^ ((row & 7) << 3)] = f2bf(aV[r] + bv);
        }
      }
    }
  }
  __syncthreads();

  // ---- P3: imp (sigmoid-mean) + unc -> gate -> s_full
  {
    const unsigned short* tu = sA + (4 + m) * 2048;
    const unsigned short* t3 = sA + (4 + 3) * 2048;
    short8 au[4], a3[4];
#pragma unroll
    for (int kt = 0; kt < 4; ++kt) {
      au[kt] = *(const short8*)(tu + ((r16 * 128 + kt * 32 + g4 * 8) ^ ((r16 & 7) << 3)));
      a3[kt] = *(const short8*)(t3 + ((r16 * 128 + kt * 32 + g4 * 8) ^ ((r16 & 7) << 3)));
    }
    const unsigned short* pkimp = pk + PK_IMP + m * 32768;
    const unsigned short* pkun = pk + PK_UNC + m * 16384;
    float impsum[4] = {0.f, 0.f, 0.f, 0.f};
    float uncsum[4] = {0.f, 0.f, 0.f, 0.f};
#pragma unroll
    for (int j = 0; j < 8; ++j) {
      f32x4 ai = {0.f, 0.f, 0.f, 0.f}, ah = {0.f, 0.f, 0.f, 0.f};
#pragma unroll
      for (int kt = 0; kt < 4; ++kt) {
        ai = __builtin_amdgcn_mfma_f32_16x16x32_bf16(au[kt], ldb(pkimp, j, kt, 8), ai, 0, 0, 0);
        ai = __builtin_amdgcn_mfma_f32_16x16x32_bf16(a3[kt], ldb(pkimp, j, kt + 4, 8), ai, 0, 0, 0);
        ah = __builtin_amdgcn_mfma_f32_16x16x32_bf16(au[kt], ldb(pkun, j, kt, 4), ah, 0, 0, 0);
      }
      const int bcol = j * 16 + r16;
      const float bi = imp_b[m * 128 + bcol];
      const float bh = unc_b1[m * 128 + bcol];
      const float w2 = unc_W2[m * 128 + bcol];
#pragma unroll
      for (int r = 0; r < 4; ++r) {
        impsum[r] += sigm(ai[r] + bi);
        uncsum[r] += fmaxf(ah[r] + bh, 0.f) * w2;
      }
    }
#pragma unroll
    for (int off = 1; off <= 8; off <<= 1) {
#pragma unroll
      for (int r = 0; r < 4; ++r) {
        impsum[r] += __shfl_xor(impsum[r], off);
        uncsum[r] += __shfl_xor(uncsum[r], off);
      }
    }
    if (g4 < 2 && r16 == 0) {
      const float b2 = unc_b2[m];
#pragma unroll
      for (int r = 0; r < 4; ++r) {
        int l = g4 * 4 + r;
        float imp = impsum[r] * (1.f / 128.f);
        float un = sigm(uncsum[r] + b2);
        float gate = sigm(2.f * imp / (1e-6f + un));
        s_full[l][m] = gate * state[(n0 + l) * 4 + m];
      }
    }
  }
  __syncthreads();

  // ---- P4: BinaryMaskSTE forward
  if (t < LOCB) {
    float f[4];
#pragma unroll
    for (int mm = 0; mm < 4; ++mm) f[mm] = s_full[t][mm];
    int bi = 0;
    float best = f[0];
#pragma unroll
    for (int mm = 1; mm < 4; ++mm)
      if (f[mm] > best) { best = f[mm]; bi = mm; }
#pragma unroll
    for (int mm = 0; mm < 4; ++mm) {
      float hard = (mm == bi || f[mm] > 0.8f) ? 1.f : 0.f;
      bm[(n0 + t) * 4 + mm] = hard * state[(n0 + t) * 4 + mm];
    }
  }

  // ---- P5: emb1 = va @ out_W
  {
    const unsigned short* tv = sA + (8 + m) * 2048;
    short8 av[4];
#pragma unroll
    for (int kt = 0; kt < 4; ++kt)
      av[kt] = *(const short8*)(tv + ((r16 * 128 + kt * 32 + g4 * 8) ^ ((r16 & 7) << 3)));
#pragma unroll
    for (int j = 0; j < 8; ++j) {
      f32x4 acc = {0.f, 0.f, 0.f, 0.f};
#pragma unroll
      for (int kt = 0; kt < 4; ++kt)
        acc = __builtin_amdgcn_mfma_f32_16x16x32_bf16(av[kt], ldb(pk + PK_OUT, j, kt, 4), acc, 0, 0, 0);
      const int bcol = j * 16 + r16;
      if (g4 < 2) {
#pragma unroll
        for (int r = 0; r < 4; ++r)
          emb1[((size_t)(n0 + g4 * 4 + r) * 4 + m) * 128 + bcol] = acc[r];
      }
    }
  }
}

// ---------------------------------------------------------------------------
extern "C" void kernel_launch(void* const* d_in, const int* in_sizes, int n_in,
                              void* d_out, int out_size, void* d_ws, size_t ws_size,
                              hipStream_t stream) {
  const float* x      = (const float*)d_in[0];
  const float* poi    = (const float*)d_in[1];
  const float* sat    = (const float*)d_in[2];
  const float* loc    = (const float*)d_in[3];
  const float* state  = (const float*)d_in[4];
  const float* poi_W  = (const float*)d_in[5];
  const float* poi_b  = (const float*)d_in[6];
  const float* poi_pe = (const float*)d_in[7];
  const float* sat_W  = (const float*)d_in[8];
  const float* sat_b  = (const float*)d_in[9];
  const float* sat_pe = (const float*)d_in[10];
  const float* xl_W   = (const float*)d_in[11];
  const float* xl_b   = (const float*)d_in[12];
  const float* x_pe   = (const float*)d_in[13];
  const float* loc_W  = (const float*)d_in[14];
  const float* loc_b  = (const float*)d_in[15];
  const float* loc_pe = (const float*)d_in[16];
  const float* q_W    = (const float*)d_in[17];
  const float* q_b    = (const float*)d_in[18];
  const float* v_W    = (const float*)d_in[19];
  const float* v_b    = (const float*)d_in[20];
  const float* imp_W  = (const float*)d_in[21];
  const float* imp_b  = (const float*)d_in[22];
  const float* unc_W1 = (const float*)d_in[23];
  const float* unc_b1 = (const float*)d_in[24];
  const float* unc_W2 = (const float*)d_in[25];
  const float* unc_b2 = (const float*)d_in[26];
  const float* out_W  = (const float*)d_in[27];

  float* out  = (float*)d_out;
  float* emb1 = out;                                   // [2048,4,128]
  float* xout = out + (size_t)2048 * 4 * 128;          // [8,2048,64,128]
  float* bm   = xout + (size_t)8 * 2048 * 64 * 128;    // [2048,4,1]

  float* cb = (float*)d_ws;                             // 128 f32
  unsigned short* ctswz = (unsigned short*)(cb + 128);  // 16384 bf16
  unsigned short* pkw   = ctswz + 16384;                // PK_TOTAL bf16

  kWA<<<dim3(KW_BLOCKS + 129), dim3(256), 0, stream>>>(
      q_W, v_W, out_W, poi_W, sat_W, loc_W, xl_W, imp_W, unc_W1,
      xl_b, x_pe, v_b, pkw, ctswz, cb);
  kB<<<dim3(256), dim3(256), 0, stream>>>(x, poi, sat, loc, state,
      poi_b, poi_pe, sat_b, sat_pe, loc_b, loc_pe, xl_b, x_pe,
      q_b, v_b, imp_b, unc_b1, unc_W2, unc_b2, pkw, emb1, bm);
  kC<<<dim3(2048), dim3(256), 0, stream>>>(x, ctswz, cb, xout);
}

// Round 6
// 252.921 us; speedup vs baseline: 1.1304x; 1.1304x over previous
//
#include <hip/hip_runtime.h>
#include <math.h>

typedef __attribute__((ext_vector_type(8))) short short8;
typedef __attribute__((ext_vector_type(4))) float f32x4;
typedef __attribute__((ext_vector_type(4))) int i32x4;

#define NN 2048
#define LL 64
#define DD 128
#define BBATCH 8
#define LOCB 8

// packed-weight offsets (bf16 element units)
#define PK_Q    0
#define PK_V    16384
#define PK_OUT  32768
#define PK_POI  49152
#define PK_SAT  57344
#define PK_LOC  73728
#define PK_XL   77824
#define PK_IMP  94208
#define PK_UNC  225280
#define PK_TOTAL 290816
#define KW_BLOCKS 1136   // PK_TOTAL / 256 exactly

// fused kernel shared-memory arena: max(kC: 33280, kB: 53376)
#define SMEM_BYTES 53376

__device__ __forceinline__ unsigned short f2bf(float f) {
  unsigned u = __float_as_uint(f);
  u += 0x7fffu + ((u >> 16) & 1u);   // round-to-nearest-even
  return (unsigned short)(u >> 16);
}
__device__ __forceinline__ float sigm(float x) { return 1.0f / (1.0f + expf(-x)); }

// RNE-pack two f32 -> one u32 of 2x bf16, via schedulable builtins (no asm).
__device__ __forceinline__ unsigned bfpair(float lo, float hi) {
  unsigned a = __float_as_uint(lo);
  unsigned b = __float_as_uint(hi);
  a += 0x7fffu + ((a >> 16) & 1u);
  b += 0x7fffu + ((b >> 16) & 1u);
  return __builtin_amdgcn_perm(b, a, 0x07060302u);
}

struct Frag { short8 v[4]; };

// ---------------------------------------------------------------------------
// kWA: merged weight-pack (blocks 0..1135) + folded-C precompute (1136..1264).
// ---------------------------------------------------------------------------
__global__ __launch_bounds__(256) void kWA(
    const float* __restrict__ q_W, const float* __restrict__ v_W,
    const float* __restrict__ out_W, const float* __restrict__ poi_W,
    const float* __restrict__ sat_W, const float* __restrict__ loc_W,
    const float* __restrict__ xl_W, const float* __restrict__ imp_W,
    const float* __restrict__ unc_W1,
    const float* __restrict__ xl_b, const float* __restrict__ x_pe,
    const float* __restrict__ v_b,
    unsigned short* __restrict__ dst,
    unsigned short* __restrict__ ctswz, float* __restrict__ cb) {
  if (blockIdx.x < KW_BLOCKS) {
    int idx = blockIdx.x * 256 + threadIdx.x;
    const float* src;
    int K, local;
    if (idx < PK_V)        { src = q_W;   K = 128; local = idx - PK_Q; }
    else if (idx < PK_OUT) { src = v_W;   K = 128; local = idx - PK_V; }
    else if (idx < PK_POI) { src = out_W; K = 128; local = idx - PK_OUT; }
    else if (idx < PK_SAT) { src = poi_W; K = 64;  local = idx - PK_POI; }
    else if (idx < PK_LOC) { src = sat_W; K = 128; local = idx - PK_SAT; }
    else if (idx < PK_XL)  { src = loc_W; K = 32;  local = idx - PK_LOC; }
    else if (idx < PK_IMP) { src = xl_W;  K = 128; local = idx - PK_XL; }
    else if (idx < PK_UNC) { int l = idx - PK_IMP; int m = l >> 15; src = imp_W + m * 256 * 128; K = 256; local = l & 32767; }
    else                   { int l = idx - PK_UNC; int m = l >> 14; src = unc_W1 + m * 128 * 128; K = 128; local = l & 16383; }
    int e = local & 7, lane = (local >> 3) & 63, rest = local >> 9;
    int KT = K >> 5;
    int kt = rest % KT, j = rest / KT;
    int k = kt * 32 + (lane >> 4) * 8 + e;
    int col = j * 16 + (lane & 15);
    dst[idx] = f2bf(src[k * 128 + col]);
  } else {
    __shared__ float s1[128];
    __shared__ float s2[128];
    const int t = threadIdx.x;
    const int k = blockIdx.x - KW_BLOCKS;  // 0..128
    if (t < 128) s1[t] = (k < 128) ? xl_W[k * 128 + t] : (xl_b[t] + x_pe[t]);
    __syncthreads();
    if (t < 128) {
      float ac[4] = {0.f, 0.f, 0.f, 0.f};
      for (int j = 0; j < 128; j += 4) {
#pragma unroll
        for (int u = 0; u < 4; ++u) ac[u] += s1[j + u] * v_W[(j + u) * 128 + t];
      }
      float a1 = (ac[0] + ac[1]) + (ac[2] + ac[3]);
      if (k == 128) a1 += v_b[t];
      s2[t] = a1;
    }
    __syncthreads();
    if (t < 128) {
      float ac[4] = {0.f, 0.f, 0.f, 0.f};
      for (int j = 0; j < 128; j += 4) {
#pragma unroll
        for (int u = 0; u < 4; ++u) ac[u] += s2[j + u] * out_W[(j + u) * 128 + t];
      }
      float a2 = (ac[0] + ac[1]) + (ac[2] + ac[3]);
      if (k < 128) {
        int byte = (t * 256 + k * 2) ^ ((t & 7) << 4);
        ctswz[byte >> 1] = f2bf(a2);
      } else {
        cb[t] = a2;
      }
    }
  }
}

// ---------------------------------------------------------------------------
// kC body: x_out = x @ C + cb, bf16 MFMA, transposed-D, depth-2 prefetch,
// plain loads/stores (R4 config — best measured).
// ---------------------------------------------------------------------------
__device__ __forceinline__ void kc_body(const float* __restrict__ x,
                                        const unsigned short* __restrict__ ctswz,
                                        const float* __restrict__ cb,
                                        float* __restrict__ out,
                                        unsigned char* smem, int bid) {
  unsigned short* lds = (unsigned short*)smem;     // 32768 B
  float* cbl = (float*)(smem + 32768);             // 512 B
  const int t = threadIdx.x;
  for (int i = t; i < 2048; i += 256)
    ((f32x4*)lds)[i] = ((const f32x4*)ctswz)[i];
  if (t < 128) cbl[t] = cb[t];
  __syncthreads();

  const int lane = t & 63;
  const int r16 = lane & 15;
  const int g4 = lane >> 4;

  int kofs[4];
#pragma unroll
  for (int kt = 0; kt < 4; ++kt)
    kofs[kt] = (kt * 64 + g4 * 16) ^ ((r16 & 7) << 4);

  const char* ldsb = (const char*)lds;
  const int gw = bid * 4 + (t >> 6);

  const float* xw = x + ((size_t)gw * 16 + r16) * 128 + g4 * 8;
  const size_t TS = (size_t)8192 * 16 * 128;  // elements per tile step

  auto loadx = [&](f32x4* r0, f32x4* r1, const float* p) {
#pragma unroll
    for (int kt = 0; kt < 4; ++kt) {
      r0[kt] = *(const f32x4*)(p + kt * 32);
      r1[kt] = *(const f32x4*)(p + kt * 32 + 4);
    }
  };

  auto pack = [&](const f32x4* r0, const f32x4* r1) -> Frag {
    Frag f;
#pragma unroll
    for (int kt = 0; kt < 4; ++kt) {
      i32x4 p;
      p[0] = (int)bfpair(r0[kt][0], r0[kt][1]);
      p[1] = (int)bfpair(r0[kt][2], r0[kt][3]);
      p[2] = (int)bfpair(r1[kt][0], r1[kt][1]);
      p[3] = (int)bfpair(r1[kt][2], r1[kt][3]);
      f.v[kt] = __builtin_bit_cast(short8, p);
    }
    return f;
  };

  auto jloop = [&](const Frag& f, int it) {
    float* orow = out + (((size_t)gw + (size_t)it * 8192) * 16 + r16) * 128 + g4 * 4;
#pragma unroll
    for (int j = 0; j < 8; ++j) {
      f32x4 acc = {0.f, 0.f, 0.f, 0.f};
      const int cbyte = (j * 16 + r16) << 8;
#pragma unroll
      for (int kt = 0; kt < 4; ++kt) {
        short8 a = *(const short8*)(ldsb + cbyte + kofs[kt]);
        acc = __builtin_amdgcn_mfma_f32_16x16x32_bf16(a, f.v[kt], acc, 0, 0, 0);
      }
      f32x4 cbj = *(const f32x4*)(cbl + j * 16 + g4 * 4);
      acc += cbj;
      *(f32x4*)(orow + j * 16) = acc;
    }
  };

  f32x4 rA0[4], rA1[4], rB0[4], rB1[4];
  loadx(rA0, rA1, xw);
  loadx(rB0, rB1, xw + TS);

#pragma unroll
  for (int it = 0; it < 8; it += 2) {
    Frag fA = pack(rA0, rA1);
    if (it + 2 < 8) loadx(rA0, rA1, xw + (size_t)(it + 2) * TS);
    jloop(fA, it);
    Frag fB = pack(rB0, rB1);
    if (it + 3 < 8) loadx(rB0, rB1, xw + (size_t)(it + 3) * TS);
    jloop(fB, it + 1);
  }
}

// ---------------------------------------------------------------------------
// kB body: MFMA selector, 256 blocks x 256 threads; block = 8 locations.
// ---------------------------------------------------------------------------
__device__ __forceinline__ short8 ldb(const unsigned short* pkW, int j, int kt, int KT) {
  return *(const short8*)(pkW + (size_t)(((j * KT + kt) * 64) + (threadIdx.x & 63)) * 8);
}

__device__ __forceinline__ void kb_body(
    const float* __restrict__ x, const float* __restrict__ poi,
    const float* __restrict__ sat, const float* __restrict__ loc,
    const float* __restrict__ state,
    const float* __restrict__ poi_b, const float* __restrict__ poi_pe,
    const float* __restrict__ sat_b, const float* __restrict__ sat_pe,
    const float* __restrict__ loc_b, const float* __restrict__ loc_pe,
    const float* __restrict__ xl_b, const float* __restrict__ x_pe,
    const float* __restrict__ q_b, const float* __restrict__ v_b,
    const float* __restrict__ imp_b, const float* __restrict__ unc_b1,
    const float* __restrict__ unc_W2, const float* __restrict__ unc_b2,
    const unsigned short* __restrict__ pk,
    float* __restrict__ emb1, float* __restrict__ bm,
    unsigned char* smem, int bid) {
  // sA: [0..3]=q tiles, [4..7]=qu tiles, [8..11]=va tiles, [12]=xb tile
  unsigned short* sA = (unsigned short*)smem;          // 13*2048*2 = 53248 B
  float (*s_full)[4] = (float(*)[4])(smem + 53248);    // 128 B

  const int t = threadIdx.x;
  const int m = t >> 6;
  const int lane = t & 63;
  const int r16 = lane & 15, g4 = lane >> 4;
  const int n0 = bid * LOCB;

  for (int i = t; i < 13 * 1024; i += 256) ((unsigned*)sA)[i] = 0u;
  __syncthreads();

  // P0: xb = mean_b x[b, n0+l, 0, :]
  for (int s = t; s < LOCB * 128; s += 256) {
    int l = s >> 7, d = s & 127;
    const float* xp = x + ((size_t)(n0 + l) * LL) * DD + d;
    float acc = 0.f;
#pragma unroll
    for (int b = 0; b < BBATCH; ++b) acc += xp[(size_t)b * NN * LL * DD];
    sA[12 * 2048 + ((l * 128 + d) ^ ((l & 7) << 3))] = f2bf(acc * 0.125f);
  }
  __syncthreads();

  // ---- P1: q[m] = input_m @ W_m + b_m + pe_m
  {
    const int KTm = (m == 0) ? 2 : ((m == 2) ? 1 : 4);
    const unsigned short* pkW =
        pk + (m == 0 ? PK_POI : m == 1 ? PK_SAT : m == 2 ? PK_LOC : PK_XL);
    const float* bb = (m == 0) ? poi_b : (m == 1) ? sat_b : (m == 2) ? loc_b : xl_b;
    const float* pe = (m == 0) ? poi_pe : (m == 1) ? sat_pe : (m == 2) ? loc_pe : x_pe;

    short8 af[4];
#pragma unroll
    for (int kt = 0; kt < 4; ++kt) af[kt] = (short8)0;
    if (m < 3) {
      const float* src = (m == 0) ? poi : (m == 1) ? sat : loc;
      const int KD = (m == 0) ? 64 : (m == 1) ? 128 : 32;
      const int locA = (r16 < LOCB) ? r16 : (LOCB - 1);
      const float* ar = src + (size_t)(n0 + locA) * KD + g4 * 8;
#pragma unroll
      for (int kt = 0; kt < 4; ++kt) {
        if (kt < KTm) {
          f32x4 v0 = *(const f32x4*)(ar + kt * 32);
          f32x4 v1 = *(const f32x4*)(ar + kt * 32 + 4);
          short8 a;
          a[0] = (short)f2bf(v0[0]); a[1] = (short)f2bf(v0[1]);
          a[2] = (short)f2bf(v0[2]); a[3] = (short)f2bf(v0[3]);
          a[4] = (short)f2bf(v1[0]); a[5] = (short)f2bf(v1[1]);
          a[6] = (short)f2bf(v1[2]); a[7] = (short)f2bf(v1[3]);
          af[kt] = a;
        }
      }
    } else {
      const unsigned short* tile = sA + 12 * 2048;
#pragma unroll
      for (int kt = 0; kt < 4; ++kt)
        af[kt] = *(const short8*)(tile + ((r16 * 128 + kt * 32 + g4 * 8) ^ ((r16 & 7) << 3)));
    }

    unsigned short* tq = sA + m * 2048;
#pragma unroll
    for (int j = 0; j < 8; ++j) {
      f32x4 acc = {0.f, 0.f, 0.f, 0.f};
#pragma unroll
      for (int kt = 0; kt < 4; ++kt)
        if (kt < KTm) acc = __builtin_amdgcn_mfma_f32_16x16x32_bf16(af[kt], ldb(pkW, j, kt, KTm), acc, 0, 0, 0);
      const int bcol = j * 16 + r16;
      const float badd = bb[bcol] + pe[bcol];
      if (g4 < 2) {
#pragma unroll
        for (int r = 0; r < 4; ++r) {
          int row = g4 * 4 + r;
          tq[(row * 128 + bcol) ^ ((row & 7) << 3)] = f2bf(acc[r] + badd);
        }
      }
    }
  }

  // ---- P2: qu = q@q_W + q_b ; va = q@v_W + v_b
  {
    const unsigned short* tile = sA + m * 2048;
    short8 aq[4];
#pragma unroll
    for (int kt = 0; kt < 4; ++kt)
      aq[kt] = *(const short8*)(tile + ((r16 * 128 + kt * 32 + g4 * 8) ^ ((r16 & 7) << 3)));
    unsigned short* tu = sA + (4 + m) * 2048;
    unsigned short* tv = sA + (8 + m) * 2048;
#pragma unroll
    for (int j = 0; j < 8; ++j) {
      f32x4 aQ = {0.f, 0.f, 0.f, 0.f}, aV = {0.f, 0.f, 0.f, 0.f};
#pragma unroll
      for (int kt = 0; kt < 4; ++kt) {
        aQ = __builtin_amdgcn_mfma_f32_16x16x32_bf16(aq[kt], ldb(pk + PK_Q, j, kt, 4), aQ, 0, 0, 0);
        aV = __builtin_amdgcn_mfma_f32_16x16x32_bf16(aq[kt], ldb(pk + PK_V, j, kt, 4), aV, 0, 0, 0);
      }
      const int bcol = j * 16 + r16;
      const float bq = q_b[bcol], bv = v_b[bcol];
      if (g4 < 2) {
#pragma unroll
        for (int r = 0; r < 4; ++r) {
          int row = g4 * 4 + r;
          tu[(row * 128 + bcol) ^ ((row & 7) << 3)] = f2bf(aQ[r] + bq);
          tv[(row * 128 + bcol) ^ ((row & 7) << 3)] = f2bf(aV[r] + bv);
        }
      }
    }
  }
  __syncthreads();

  // ---- P3: imp (sigmoid-mean) + unc -> gate -> s_full
  {
    const unsigned short* tu = sA + (4 + m) * 2048;
    const unsigned short* t3 = sA + (4 + 3) * 2048;
    short8 au[4], a3[4];
#pragma unroll
    for (int kt = 0; kt < 4; ++kt) {
      au[kt] = *(const short8*)(tu + ((r16 * 128 + kt * 32 + g4 * 8) ^ ((r16 & 7) << 3)));
      a3[kt] = *(const short8*)(t3 + ((r16 * 128 + kt * 32 + g4 * 8) ^ ((r16 & 7) << 3)));
    }
    const unsigned short* pkimp = pk + PK_IMP + m * 32768;
    const unsigned short* pkun = pk + PK_UNC + m * 16384;
    float impsum[4] = {0.f, 0.f, 0.f, 0.f};
    float uncsum[4] = {0.f, 0.f, 0.f, 0.f};
#pragma unroll
    for (int j = 0; j < 8; ++j) {
      f32x4 ai = {0.f, 0.f, 0.f, 0.f}, ah = {0.f, 0.f, 0.f, 0.f};
#pragma unroll
      for (int kt = 0; kt < 4; ++kt) {
        ai = __builtin_amdgcn_mfma_f32_16x16x32_bf16(au[kt], ldb(pkimp, j, kt, 8), ai, 0, 0, 0);
        ai = __builtin_amdgcn_mfma_f32_16x16x32_bf16(a3[kt], ldb(pkimp, j, kt + 4, 8), ai, 0, 0, 0);
        ah = __builtin_amdgcn_mfma_f32_16x16x32_bf16(au[kt], ldb(pkun, j, kt, 4), ah, 0, 0, 0);
      }
      const int bcol = j * 16 + r16;
      const float bi = imp_b[m * 128 + bcol];
      const float bh = unc_b1[m * 128 + bcol];
      const float w2 = unc_W2[m * 128 + bcol];
#pragma unroll
      for (int r = 0; r < 4; ++r) {
        impsum[r] += sigm(ai[r] + bi);
        uncsum[r] += fmaxf(ah[r] + bh, 0.f) * w2;
      }
    }
#pragma unroll
    for (int off = 1; off <= 8; off <<= 1) {
#pragma unroll
      for (int r = 0; r < 4; ++r) {
        impsum[r] += __shfl_xor(impsum[r], off);
        uncsum[r] += __shfl_xor(uncsum[r], off);
      }
    }
    if (g4 < 2 && r16 == 0) {
      const float b2 = unc_b2[m];
#pragma unroll
      for (int r = 0; r < 4; ++r) {
        int l = g4 * 4 + r;
        float imp = impsum[r] * (1.f / 128.f);
        float un = sigm(uncsum[r] + b2);
        float gate = sigm(2.f * imp / (1e-6f + un));
        s_full[l][m] = gate * state[(n0 + l) * 4 + m];
      }
    }
  }
  __syncthreads();

  // ---- P4: BinaryMaskSTE forward
  if (t < LOCB) {
    float f[4];
#pragma unroll
    for (int mm = 0; mm < 4; ++mm) f[mm] = s_full[t][mm];
    int bi = 0;
    float best = f[0];
#pragma unroll
    for (int mm = 1; mm < 4; ++mm)
      if (f[mm] > best) { best = f[mm]; bi = mm; }
#pragma unroll
    for (int mm = 0; mm < 4; ++mm) {
      float hard = (mm == bi || f[mm] > 0.8f) ? 1.f : 0.f;
      bm[(n0 + t) * 4 + mm] = hard * state[(n0 + t) * 4 + mm];
    }
  }

  // ---- P5: emb1 = va @ out_W
  {
    const unsigned short* tv = sA + (8 + m) * 2048;
    short8 av[4];
#pragma unroll
    for (int kt = 0; kt < 4; ++kt)
      av[kt] = *(const short8*)(tv + ((r16 * 128 + kt * 32 + g4 * 8) ^ ((r16 & 7) << 3)));
#pragma unroll
    for (int j = 0; j < 8; ++j) {
      f32x4 acc = {0.f, 0.f, 0.f, 0.f};
#pragma unroll
      for (int kt = 0; kt < 4; ++kt)
        acc = __builtin_amdgcn_mfma_f32_16x16x32_bf16(av[kt], ldb(pk + PK_OUT, j, kt, 4), acc, 0, 0, 0);
      const int bcol = j * 16 + r16;
      if (g4 < 2) {
#pragma unroll
        for (int r = 0; r < 4; ++r)
          emb1[((size_t)(n0 + g4 * 4 + r) * 4 + m) * 128 + bcol] = acc[r];
      }
    }
  }
}

// ---------------------------------------------------------------------------
// kCB: fused stream kernel. Blocks [0,2048) = kC; [2048,2304) = kB.
// kB blocks dispatch after kC's wavefront -> latency-bound selector work
// overlaps the BW-bound tail for free.
// ---------------------------------------------------------------------------
__global__ __launch_bounds__(256) void kCB(
    const float* __restrict__ x,
    const unsigned short* __restrict__ ctswz, const float* __restrict__ cb,
    float* __restrict__ xout,
    const float* __restrict__ poi, const float* __restrict__ sat,
    const float* __restrict__ loc, const float* __restrict__ state,
    const float* __restrict__ poi_b, const float* __restrict__ poi_pe,
    const float* __restrict__ sat_b, const float* __restrict__ sat_pe,
    const float* __restrict__ loc_b, const float* __restrict__ loc_pe,
    const float* __restrict__ xl_b, const float* __restrict__ x_pe,
    const float* __restrict__ q_b, const float* __restrict__ v_b,
    const float* __restrict__ imp_b, const float* __restrict__ unc_b1,
    const float* __restrict__ unc_W2, const float* __restrict__ unc_b2,
    const unsigned short* __restrict__ pk,
    float* __restrict__ emb1, float* __restrict__ bm) {
  __shared__ __align__(16) unsigned char smem[SMEM_BYTES];
  if (blockIdx.x < 2048) {
    kc_body(x, ctswz, cb, xout, smem, blockIdx.x);
  } else {
    kb_body(x, poi, sat, loc, state, poi_b, poi_pe, sat_b, sat_pe,
            loc_b, loc_pe, xl_b, x_pe, q_b, v_b, imp_b, unc_b1,
            unc_W2, unc_b2, pk, emb1, bm, smem, blockIdx.x - 2048);
  }
}

// ---------------------------------------------------------------------------
extern "C" void kernel_launch(void* const* d_in, const int* in_sizes, int n_in,
                              void* d_out, int out_size, void* d_ws, size_t ws_size,
                              hipStream_t stream) {
  const float* x      = (const float*)d_in[0];
  const float* poi    = (const float*)d_in[1];
  const float* sat    = (const float*)d_in[2];
  const float* loc    = (const float*)d_in[3];
  const float* state  = (const float*)d_in[4];
  const float* poi_W  = (const float*)d_in[5];
  const float* poi_b  = (const float*)d_in[6];
  const float* poi_pe = (const float*)d_in[7];
  const float* sat_W  = (const float*)d_in[8];
  const float* sat_b  = (const float*)d_in[9];
  const float* sat_pe = (const float*)d_in[10];
  const float* xl_W   = (const float*)d_in[11];
  const float* xl_b   = (const float*)d_in[12];
  const float* x_pe   = (const float*)d_in[13];
  const float* loc_W  = (const float*)d_in[14];
  const float* loc_b  = (const float*)d_in[15];
  const float* loc_pe = (const float*)d_in[16];
  const float* q_W    = (const float*)d_in[17];
  const float* q_b    = (const float*)d_in[18];
  const float* v_W    = (const float*)d_in[19];
  const float* v_b    = (const float*)d_in[20];
  const float* imp_W  = (const float*)d_in[21];
  const float* imp_b  = (const float*)d_in[22];
  const float* unc_W1 = (const float*)d_in[23];
  const float* unc_b1 = (const float*)d_in[24];
  const float* unc_W2 = (const float*)d_in[25];
  const float* unc_b2 = (const float*)d_in[26];
  const float* out_W  = (const float*)d_in[27];

  float* out  = (float*)d_out;
  float* emb1 = out;                                   // [2048,4,128]
  float* xout = out + (size_t)2048 * 4 * 128;          // [8,2048,64,128]
  float* bm   = xout + (size_t)8 * 2048 * 64 * 128;    // [2048,4,1]

  float* cb = (float*)d_ws;                             // 128 f32
  unsigned short* ctswz = (unsigned short*)(cb + 128);  // 16384 bf16
  unsigned short* pkw   = ctswz + 16384;                // PK_TOTAL bf16

  kWA<<<dim3(KW_BLOCKS + 129), dim3(256), 0, stream>>>(
      q_W, v_W, out_W, poi_W, sat_W, loc_W, xl_W, imp_W, unc_W1,
      xl_b, x_pe, v_b, pkw, ctswz, cb);
  kCB<<<dim3(2048 + 256), dim3(256), 0, stream>>>(
      x, ctswz, cb, xout, poi, sat, loc, state,
      poi_b, poi_pe, sat_b, sat_pe, loc_b, loc_pe, xl_b, x_pe,
      q_b, v_b, imp_b, unc_b1, unc_W2, unc_b2, pkw, emb1, bm);
}